// Round 2
// baseline (907.532 us; speedup 1.0000x reference)
//
#include <hip/hip_runtime.h>
#include <hip/hip_bf16.h>
#include <cstdint>
#include <cstddef>

#define N_ACT 200000
#define CH 128
#define NOFF 27
#define TM 128

typedef __bf16 v8bf __attribute__((ext_vector_type(8)));
typedef float v4f __attribute__((ext_vector_type(4)));

__device__ __forceinline__ unsigned short f2bf(float f) {
    union { float f; unsigned int u; } x; x.f = f;
    unsigned int lsb = (x.u >> 16) & 1u;
    x.u += 0x7fffu + lsb;            // round-to-nearest-even
    return (unsigned short)(x.u >> 16);
}

// K1a: cast features fp32 -> bf16, 8 elements/thread
__global__ void cast_feat(const float* __restrict__ in,
                          unsigned short* __restrict__ out) {
    long long i = (long long)blockIdx.x * blockDim.x + threadIdx.x;
    long long base = i * 8;
    if (base >= (long long)N_ACT * CH) return;
    const float4* p = (const float4*)(in + base);
    float4 a = p[0], b = p[1];
    unsigned int w0 = (unsigned)f2bf(a.x) | ((unsigned)f2bf(a.y) << 16);
    unsigned int w1 = (unsigned)f2bf(a.z) | ((unsigned)f2bf(a.w) << 16);
    unsigned int w2 = (unsigned)f2bf(b.x) | ((unsigned)f2bf(b.y) << 16);
    unsigned int w3 = (unsigned)f2bf(b.z) | ((unsigned)f2bf(b.w) << 16);
    *(uint4*)(out + base) = make_uint4(w0, w1, w2, w3);
}

// K1b: W[k][cin][cout] fp32 -> Wt[k][cout][cin] bf16; block 0 zeros stats+zpage
__global__ void prep_w(const float* __restrict__ W,
                       unsigned short* __restrict__ Wt,
                       float* __restrict__ stats,
                       float* __restrict__ zpage) {
    int k = blockIdx.x;
    int t = threadIdx.x;
    if (k == 0 && t < 2 * CH) stats[t] = 0.0f;   // sums + sumsq
    if (k == 0 && t < 16) zpage[t] = 0.0f;       // 64B zero page for gathers
    const float* wk = W + (size_t)k * CH * CH;
    unsigned short* wo = Wt + (size_t)k * CH * CH;
    for (int g = t; g < CH * CH / 8; g += blockDim.x) {
        int co  = g >> 4;            // output channel (row of Wt)
        int ci0 = (g & 15) * 8;      // 8 consecutive input channels
        unsigned int wbuf[4];
        #pragma unroll
        for (int h = 0; h < 4; ++h) {
            unsigned short lo = f2bf(wk[(size_t)(ci0 + 2*h)     * CH + co]);
            unsigned short hi = f2bf(wk[(size_t)(ci0 + 2*h + 1) * CH + co]);
            wbuf[h] = (unsigned)lo | ((unsigned)hi << 16);
        }
        *(uint4*)(wo + (size_t)co * CH + ci0) =
            make_uint4(wbuf[0], wbuf[1], wbuf[2], wbuf[3]);
    }
}

// K2: pipelined gather + MFMA over 27 offsets.
// A staged via global_load_lds into fragment-ordered double buffer:
//   bufA[buf][c8][row][8 bf16]  (plane stride 2048B -> conflict-free b128 reads)
// B fragments register-double-buffered. One barrier per k.
__global__ __launch_bounds__(256, 2) void conv_mfma(
        const unsigned short* __restrict__ feat,   // [N][128] bf16
        const int* __restrict__ nbr,               // [27][N]
        const unsigned short* __restrict__ Wt,     // [27][cout][cin] bf16
        const unsigned short* __restrict__ zpage,  // 16B of zeros
        float* __restrict__ out,                   // [N][128] conv result
        float* __restrict__ stats) {               // sums[128], sumsq[128]
    __shared__ __bf16 bufA[2][16][TM][8];          // 2 x 32 KB
    __shared__ int idxL[NOFF * TM];                // 13.8 KB (reused as sred)

    const int t    = threadIdx.x;
    const int row0 = blockIdx.x * TM;
    const int wid  = t >> 6;
    const int lane = t & 63;
    const int wr   = (wid >> 1) * 64;   // wave row offset in tile
    const int wc   = (wid & 1) * 64;    // wave col offset in tile
    const int lr   = lane & 15;
    const int quad = lane >> 4;

    // ---- stage the whole neighbor-index table once (coalesced)
    for (int e = t; e < NOFF * TM; e += 256) {
        int k = e >> 7, r = e & 127;
        int gr = row0 + r;
        idxL[e] = (gr < N_ACT) ? nbr[(size_t)k * N_ACT + gr] : -1;
    }
    __syncthreads();

    v4f acc[4][4];
    #pragma unroll
    for (int i = 0; i < 4; ++i)
        #pragma unroll
        for (int j = 0; j < 4; ++j)
            acc[i][j] = (v4f){0.f, 0.f, 0.f, 0.f};

    v8bf bq0[16], bq1[16];

    // issue 8 async 16B gathers: wave wid covers half-planes h = wid*8+p
    auto issueA = [&](int kNext, __bf16 (*buf)[TM][8]) {
        #pragma unroll
        for (int p = 0; p < 8; ++p) {
            int h    = wid * 8 + p;
            int c8   = h >> 1;
            int half = h & 1;
            int row  = half * 64 + lane;
            int idx  = idxL[kNext * TM + row];
            const unsigned short* g = (idx >= 0)
                ? feat + ((size_t)idx << 7) + c8 * 8 : zpage;
            __builtin_amdgcn_global_load_lds(
                (const __attribute__((address_space(1))) unsigned int*)g,
                (__attribute__((address_space(3))) unsigned int*)&buf[c8][half * 64][0],
                16, 0, 0);   // HW scatters: lane L -> base + 16*L
        }
    };
    auto loadB = [&](int kNext, v8bf* dst) {
        const unsigned short* wk = Wt + (size_t)kNext * CH * CH;
        #pragma unroll
        for (int j = 0; j < 4; ++j)
            #pragma unroll
            for (int q = 0; q < 4; ++q)
                dst[j * 4 + q] = *(const v8bf*)(
                    wk + (size_t)(wc + j * 16 + lr) * CH + q * 32 + quad * 8);
    };
    auto mfmaPhase = [&](__bf16 (*buf)[TM][8], v8bf* bq) {
        #pragma unroll
        for (int kk = 0; kk < 4; ++kk) {
            v8bf a[4];
            #pragma unroll
            for (int i = 0; i < 4; ++i)
                a[i] = *(const v8bf*)&buf[kk * 4 + quad][wr + i * 16 + lr][0];
            #pragma unroll
            for (int i = 0; i < 4; ++i)
                #pragma unroll
                for (int j = 0; j < 4; ++j)
                    acc[i][j] = __builtin_amdgcn_mfma_f32_16x16x32_bf16(
                        a[i], bq[j * 4 + kk], acc[i][j], 0, 0, 0);
        }
    };

    // prologue
    issueA(0, bufA[0]);
    loadB(0, bq0);

    // pipelined k-loop, manually unrolled x2 so buffer indices are literal
    for (int k = 0; k < NOFF; k += 2) {
        __syncthreads();                 // drains A(k)/B(k) loads
        if (k + 1 < NOFF) { issueA(k + 1, bufA[1]); loadB(k + 1, bq1); }
        mfmaPhase(bufA[0], bq0);
        if (k + 1 >= NOFF) break;
        __syncthreads();                 // drains A(k+1)/B(k+1) loads
        if (k + 2 < NOFF) { issueA(k + 2, bufA[0]); loadB(k + 2, bq0); }
        mfmaPhase(bufA[1], bq1);
    }

    // ---- epilogue: store conv result + per-column partial stats
    float psum[4] = {0.f, 0.f, 0.f, 0.f};
    float psq[4]  = {0.f, 0.f, 0.f, 0.f};
    #pragma unroll
    for (int i = 0; i < 4; ++i) {
        #pragma unroll
        for (int r = 0; r < 4; ++r) {
            int grow = row0 + wr + i * 16 + quad * 4 + r;
            if (grow < N_ACT) {
                #pragma unroll
                for (int j = 0; j < 4; ++j) {
                    float v = acc[i][j][r];
                    out[(size_t)grow * CH + wc + j * 16 + lr] = v;
                    psum[j] += v;
                    psq[j]  += v * v;
                }
            }
        }
    }
    #pragma unroll
    for (int j = 0; j < 4; ++j) {
        psum[j] += __shfl_xor(psum[j], 16, 64);
        psq[j]  += __shfl_xor(psq[j], 16, 64);
        psum[j] += __shfl_xor(psum[j], 32, 64);
        psq[j]  += __shfl_xor(psq[j], 32, 64);
    }
    // reuse idxL as reduction scratch (all idx reads drained by last barrier)
    float* sred = (float*)idxL;   // [0..255]=sum[c][half], [256..511]=sq
    if (quad == 0) {
        #pragma unroll
        for (int j = 0; j < 4; ++j) {
            int c = wc + j * 16 + lr;
            sred[c * 2 + (wid >> 1)]       = psum[j];
            sred[256 + c * 2 + (wid >> 1)] = psq[j];
        }
    }
    __syncthreads();
    if (t < CH) {
        atomicAdd(&stats[t],      sred[t * 2] + sred[t * 2 + 1]);
        atomicAdd(&stats[CH + t], sred[256 + t * 2] + sred[256 + t * 2 + 1]);
    }
}

// K3: per-channel scale/shift from batch stats
__global__ void finalize_stats(const float* __restrict__ gamma,
                               const float* __restrict__ beta,
                               float* __restrict__ stats) {
    int c = threadIdx.x;
    if (c < CH) {
        float inv_n = 1.0f / (float)N_ACT;
        float mean  = stats[c] * inv_n;
        float var   = stats[CH + c] * inv_n - mean * mean;
        float sc    = gamma[c] * rsqrtf(var + 1e-4f);
        stats[2 * CH + c] = sc;
        stats[3 * CH + c] = beta[c] - mean * sc;
    }
}

// K4: out = relu(conv * scale[c] + shift[c]), float4
__global__ void bn_relu(const float* __restrict__ conv,
                        const float* __restrict__ stats,
                        float* __restrict__ out) {
    long long i = (long long)blockIdx.x * blockDim.x + threadIdx.x;
    if (i >= (long long)N_ACT * CH / 4) return;
    int c4 = (int)(i & 31) * 4;
    float4 v  = ((const float4*)conv)[i];
    float4 sc = *(const float4*)(stats + 2 * CH + c4);
    float4 sh = *(const float4*)(stats + 3 * CH + c4);
    float4 o;
    o.x = fmaxf(v.x * sc.x + sh.x, 0.f);
    o.y = fmaxf(v.y * sc.y + sh.y, 0.f);
    o.z = fmaxf(v.z * sc.z + sh.z, 0.f);
    o.w = fmaxf(v.w * sc.w + sh.w, 0.f);
    ((float4*)out)[i] = o;
}

extern "C" void kernel_launch(void* const* d_in, const int* in_sizes, int n_in,
                              void* d_out, int out_size, void* d_ws, size_t ws_size,
                              hipStream_t stream) {
    const float* features = (const float*)d_in[0];
    const int*   nbr      = (const int*)d_in[1];
    const float* W        = (const float*)d_in[2];
    const float* gamma    = (const float*)d_in[3];
    const float* beta     = (const float*)d_in[4];
    float* outp = (float*)d_out;

    char* ws = (char*)d_ws;
    // layout: feat_bf16 (51,200,000 B) | Wt (884,736 B) | conv fp32
    // (102,400,000 B) | stats (512 floats) | zero page (64 B)
    unsigned short* feat_bf = (unsigned short*)ws;
    unsigned short* Wt      = (unsigned short*)(ws + 51200000);
    float* conv             = (float*)(ws + 51200000 + 884736);
    float* stats            = (float*)(ws + 51200000 + 884736 + 102400000);
    float* zpage            = stats + 4 * CH;

    cast_feat<<<12500, 256, 0, stream>>>(features, feat_bf);
    prep_w<<<NOFF, 256, 0, stream>>>(W, Wt, stats, zpage);
    conv_mfma<<<(N_ACT + TM - 1) / TM, 256, 0, stream>>>(
        feat_bf, nbr, Wt, (const unsigned short*)zpage, conv, stats);
    finalize_stats<<<1, CH, 0, stream>>>(gamma, beta, stats);
    bn_relu<<<25000, 256, 0, stream>>>(conv, stats, outp);
}

// Round 3
// 894.951 us; speedup vs baseline: 1.0141x; 1.0141x over previous
//
#include <hip/hip_runtime.h>
#include <hip/hip_bf16.h>
#include <cstdint>
#include <cstddef>

#define N_ACT 200000
#define CH 128
#define NOFF 27
#define TM 128
#define PLANE 1032   // plane stride in bf16 elems (2064 B = 16B-aligned, 4-dword skew)

typedef __bf16 v8bf __attribute__((ext_vector_type(8)));
typedef float v4f __attribute__((ext_vector_type(4)));

__device__ __forceinline__ unsigned short f2bf(float f) {
    union { float f; unsigned int u; } x; x.f = f;
    unsigned int lsb = (x.u >> 16) & 1u;
    x.u += 0x7fffu + lsb;            // round-to-nearest-even
    return (unsigned short)(x.u >> 16);
}

// K1a: cast features fp32 -> bf16, 8 elements/thread
__global__ void cast_feat(const float* __restrict__ in,
                          unsigned short* __restrict__ out) {
    long long i = (long long)blockIdx.x * blockDim.x + threadIdx.x;
    long long base = i * 8;
    if (base >= (long long)N_ACT * CH) return;
    const float4* p = (const float4*)(in + base);
    float4 a = p[0], b = p[1];
    unsigned int w0 = (unsigned)f2bf(a.x) | ((unsigned)f2bf(a.y) << 16);
    unsigned int w1 = (unsigned)f2bf(a.z) | ((unsigned)f2bf(a.w) << 16);
    unsigned int w2 = (unsigned)f2bf(b.x) | ((unsigned)f2bf(b.y) << 16);
    unsigned int w3 = (unsigned)f2bf(b.z) | ((unsigned)f2bf(b.w) << 16);
    *(uint4*)(out + base) = make_uint4(w0, w1, w2, w3);
}

// K1b: W[k][cin][cout] fp32 -> Wt[k][cout][cin] bf16; block 0 zeros stats+zpage
__global__ void prep_w(const float* __restrict__ W,
                       unsigned short* __restrict__ Wt,
                       float* __restrict__ stats,
                       float* __restrict__ zpage) {
    int k = blockIdx.x;
    int t = threadIdx.x;
    if (k == 0 && t < 2 * CH) stats[t] = 0.0f;   // sums + sumsq
    if (k == 0 && t < 64) zpage[t] = 0.0f;       // 256 B zero row for gathers
    const float* wk = W + (size_t)k * CH * CH;
    unsigned short* wo = Wt + (size_t)k * CH * CH;
    for (int g = t; g < CH * CH / 8; g += blockDim.x) {
        int co  = g >> 4;            // output channel (row of Wt)
        int ci0 = (g & 15) * 8;      // 8 consecutive input channels
        unsigned int wbuf[4];
        #pragma unroll
        for (int h = 0; h < 4; ++h) {
            unsigned short lo = f2bf(wk[(size_t)(ci0 + 2*h)     * CH + co]);
            unsigned short hi = f2bf(wk[(size_t)(ci0 + 2*h + 1) * CH + co]);
            wbuf[h] = (unsigned)lo | ((unsigned)hi << 16);
        }
        *(uint4*)(wo + (size_t)co * CH + ci0) =
            make_uint4(wbuf[0], wbuf[1], wbuf[2], wbuf[3]);
    }
}

// K2: pipelined gather + MFMA over 27 offsets.
//  - A gathered row-contiguously (16 lanes = one full 256B row) into VGPRs,
//    then ds_write_b128 into fragment-ordered skewed planes (conflict-free).
//  - B register-double-buffered straight from L2-resident Wt.
//  - One barrier per k; gathers for k+1 hide under MFMA phase of k.
__global__ __launch_bounds__(256, 2) void conv_mfma(
        const unsigned short* __restrict__ feat,   // [N][128] bf16
        const int* __restrict__ nbr,               // [27][N]
        const unsigned short* __restrict__ Wt,     // [27][cout][cin] bf16
        const unsigned short* __restrict__ zpage,  // 256 B of zeros
        float* __restrict__ out,                   // [N][128] conv result
        float* __restrict__ stats) {               // sums[128], sumsq[128]
    __shared__ __bf16 As[2][16 * PLANE];           // 2 x 33,024 B
    __shared__ int idxL[NOFF * TM];                // 13,824 B (reused as sred)

    const int t    = threadIdx.x;
    const int row0 = blockIdx.x * TM;
    const int wid  = t >> 6;
    const int lane = t & 63;
    const int wr   = (wid >> 1) * 64;   // wave row offset in tile
    const int wc   = (wid & 1) * 64;    // wave col offset in tile
    const int lr   = lane & 15;
    const int quad = lane >> 4;

    // ---- stage the whole neighbor-index table once (coalesced)
    for (int e = t; e < NOFF * TM; e += 256) {
        int k = e >> 7, r = e & 127;
        int gr = row0 + r;
        idxL[e] = (gr < N_ACT) ? nbr[(size_t)k * N_ACT + gr] : -1;
    }
    __syncthreads();

    v4f acc[4][4];
    #pragma unroll
    for (int i = 0; i < 4; ++i)
        #pragma unroll
        for (int j = 0; j < 4; ++j)
            acc[i][j] = (v4f){0.f, 0.f, 0.f, 0.f};

    // staging coords: thread t handles chunk sc (16B) of rows p*16+sr0
    const int sc  = t & 15;
    const int sr0 = t >> 4;
    const unsigned short* zsrc = zpage + sc * 8;

    uint4 G[8];          // gathered A rows in flight
    v8bf bq[2][16];      // B fragment double buffer

    auto issueG = [&](int k) {
        #pragma unroll
        for (int p = 0; p < 8; ++p) {
            int idx = idxL[k * TM + p * 16 + sr0];
            const unsigned short* src =
                (idx >= 0) ? feat + ((size_t)idx << 7) + sc * 8 : zsrc;
            G[p] = *(const uint4*)src;
        }
    };
    auto writeG = [&](__bf16* buf) {
        #pragma unroll
        for (int p = 0; p < 8; ++p)
            *(uint4*)(buf + sc * PLANE + (p * 16 + sr0) * 8) = G[p];
    };
    auto loadB = [&](int k, v8bf* dst) {
        const unsigned short* wk = Wt + (size_t)k * CH * CH
                                 + (size_t)(wc + lr) * CH + quad * 8;
        #pragma unroll
        for (int j = 0; j < 4; ++j)
            #pragma unroll
            for (int q = 0; q < 4; ++q)
                dst[j * 4 + q] = *(const v8bf*)(wk + j * 16 * CH + q * 32);
    };
    auto mfmaPhase = [&](const __bf16* buf, const v8bf* bqc) {
        #pragma unroll
        for (int kk = 0; kk < 4; ++kk) {
            v8bf a[4];
            #pragma unroll
            for (int i = 0; i < 4; ++i)
                a[i] = *(const v8bf*)(buf + (kk * 4 + quad) * PLANE
                                          + (wr + i * 16 + lr) * 8);
            #pragma unroll
            for (int i = 0; i < 4; ++i)
                #pragma unroll
                for (int j = 0; j < 4; ++j)
                    acc[i][j] = __builtin_amdgcn_mfma_f32_16x16x32_bf16(
                        a[i], bqc[j * 4 + kk], acc[i][j], 0, 0, 0);
        }
    };

    // ---- prologue: fill buffer 0 / B(0)
    issueG(0);
    loadB(0, bq[0]);
    writeG(As[0]);
    __syncthreads();

    // ---- pipelined k-loop, fully unrolled so buffer indices are literal
    #pragma unroll
    for (int k = 0; k < NOFF; ++k) {
        const int cur = k & 1, nxt = cur ^ 1;
        if (k + 1 < NOFF) { issueG(k + 1); loadB(k + 1, bq[nxt]); }
        mfmaPhase(As[cur], bq[cur]);
        if (k + 1 < NOFF) {
            writeG(As[nxt]);     // waits only on G(k+1) gathers
            __syncthreads();     // single barrier per k
        }
    }

    // ---- epilogue: store conv result + per-column partial stats
    float psum[4] = {0.f, 0.f, 0.f, 0.f};
    float psq[4]  = {0.f, 0.f, 0.f, 0.f};
    #pragma unroll
    for (int i = 0; i < 4; ++i) {
        #pragma unroll
        for (int r = 0; r < 4; ++r) {
            int grow = row0 + wr + i * 16 + quad * 4 + r;
            if (grow < N_ACT) {
                #pragma unroll
                for (int j = 0; j < 4; ++j) {
                    float v = acc[i][j][r];
                    out[(size_t)grow * CH + wc + j * 16 + lr] = v;
                    psum[j] += v;
                    psq[j]  += v * v;
                }
            }
        }
    }
    #pragma unroll
    for (int j = 0; j < 4; ++j) {
        psum[j] += __shfl_xor(psum[j], 16, 64);
        psq[j]  += __shfl_xor(psq[j], 16, 64);
        psum[j] += __shfl_xor(psum[j], 32, 64);
        psq[j]  += __shfl_xor(psq[j], 32, 64);
    }
    // reuse idxL as reduction scratch (all idx reads done before last barrier)
    float* sred = (float*)idxL;   // [0..255]=sum[c][half], [256..511]=sq
    if (quad == 0) {
        #pragma unroll
        for (int j = 0; j < 4; ++j) {
            int c = wc + j * 16 + lr;
            sred[c * 2 + (wid >> 1)]       = psum[j];
            sred[256 + c * 2 + (wid >> 1)] = psq[j];
        }
    }
    __syncthreads();
    if (t < CH) {
        atomicAdd(&stats[t],      sred[t * 2] + sred[t * 2 + 1]);
        atomicAdd(&stats[CH + t], sred[256 + t * 2] + sred[256 + t * 2 + 1]);
    }
}

// K3: per-channel scale/shift from batch stats
__global__ void finalize_stats(const float* __restrict__ gamma,
                               const float* __restrict__ beta,
                               float* __restrict__ stats) {
    int c = threadIdx.x;
    if (c < CH) {
        float inv_n = 1.0f / (float)N_ACT;
        float mean  = stats[c] * inv_n;
        float var   = stats[CH + c] * inv_n - mean * mean;
        float sc    = gamma[c] * rsqrtf(var + 1e-4f);
        stats[2 * CH + c] = sc;
        stats[3 * CH + c] = beta[c] - mean * sc;
    }
}

// K4: out = relu(conv * scale[c] + shift[c]), float4
__global__ void bn_relu(const float* __restrict__ conv,
                        const float* __restrict__ stats,
                        float* __restrict__ out) {
    long long i = (long long)blockIdx.x * blockDim.x + threadIdx.x;
    if (i >= (long long)N_ACT * CH / 4) return;
    int c4 = (int)(i & 31) * 4;
    float4 v  = ((const float4*)conv)[i];
    float4 sc = *(const float4*)(stats + 2 * CH + c4);
    float4 sh = *(const float4*)(stats + 3 * CH + c4);
    float4 o;
    o.x = fmaxf(v.x * sc.x + sh.x, 0.f);
    o.y = fmaxf(v.y * sc.y + sh.y, 0.f);
    o.z = fmaxf(v.z * sc.z + sh.z, 0.f);
    o.w = fmaxf(v.w * sc.w + sh.w, 0.f);
    ((float4*)out)[i] = o;
}

extern "C" void kernel_launch(void* const* d_in, const int* in_sizes, int n_in,
                              void* d_out, int out_size, void* d_ws, size_t ws_size,
                              hipStream_t stream) {
    const float* features = (const float*)d_in[0];
    const int*   nbr      = (const int*)d_in[1];
    const float* W        = (const float*)d_in[2];
    const float* gamma    = (const float*)d_in[3];
    const float* beta     = (const float*)d_in[4];
    float* outp = (float*)d_out;

    char* ws = (char*)d_ws;
    // layout: feat_bf16 (51,200,000 B) | Wt (884,736 B) | conv fp32
    // (102,400,000 B) | stats (512 floats) | zero page (256 B)
    unsigned short* feat_bf = (unsigned short*)ws;
    unsigned short* Wt      = (unsigned short*)(ws + 51200000);
    float* conv             = (float*)(ws + 51200000 + 884736);
    float* stats            = (float*)(ws + 51200000 + 884736 + 102400000);
    float* zpage            = stats + 4 * CH;

    cast_feat<<<12500, 256, 0, stream>>>(features, feat_bf);
    prep_w<<<NOFF, 256, 0, stream>>>(W, Wt, stats, zpage);
    conv_mfma<<<(N_ACT + TM - 1) / TM, 256, 0, stream>>>(
        feat_bf, nbr, Wt, (const unsigned short*)zpage, conv, stats);
    finalize_stats<<<1, CH, 0, stream>>>(gamma, beta, stats);
    bn_relu<<<25000, 256, 0, stream>>>(conv, stats, outp);
}

// Round 4
// 771.763 us; speedup vs baseline: 1.1759x; 1.1596x over previous
//
#include <hip/hip_runtime.h>
#include <hip/hip_bf16.h>
#include <cstdint>
#include <cstddef>

#define N_ACT 200000
#define CH 128
#define NOFF 27
#define TM 128

typedef __bf16 v8bf __attribute__((ext_vector_type(8)));
typedef float v4f __attribute__((ext_vector_type(4)));

__device__ __forceinline__ unsigned short f2bf(float f) {
    union { float f; unsigned int u; } x; x.f = f;
    unsigned int lsb = (x.u >> 16) & 1u;
    x.u += 0x7fffu + lsb;            // round-to-nearest-even
    return (unsigned short)(x.u >> 16);
}

// K1a: cast features fp32 -> bf16, 8 elements/thread
__global__ void cast_feat(const float* __restrict__ in,
                          unsigned short* __restrict__ out) {
    long long i = (long long)blockIdx.x * blockDim.x + threadIdx.x;
    long long base = i * 8;
    if (base >= (long long)N_ACT * CH) return;
    const float4* p = (const float4*)(in + base);
    float4 a = p[0], b = p[1];
    unsigned int w0 = (unsigned)f2bf(a.x) | ((unsigned)f2bf(a.y) << 16);
    unsigned int w1 = (unsigned)f2bf(a.z) | ((unsigned)f2bf(a.w) << 16);
    unsigned int w2 = (unsigned)f2bf(b.x) | ((unsigned)f2bf(b.y) << 16);
    unsigned int w3 = (unsigned)f2bf(b.z) | ((unsigned)f2bf(b.w) << 16);
    *(uint4*)(out + base) = make_uint4(w0, w1, w2, w3);
}

// K1b: W[k][cin][cout] fp32 -> Wt[k][cout][cin] bf16; block 0 zeros stats+zpage
__global__ void prep_w(const float* __restrict__ W,
                       unsigned short* __restrict__ Wt,
                       float* __restrict__ stats,
                       float* __restrict__ zpage) {
    int k = blockIdx.x;
    int t = threadIdx.x;
    if (k == 0 && t < 2 * CH) stats[t] = 0.0f;   // sums + sumsq
    if (k == 0 && t < 64) zpage[t] = 0.0f;       // 256 B zero row for gathers
    const float* wk = W + (size_t)k * CH * CH;
    unsigned short* wo = Wt + (size_t)k * CH * CH;
    for (int g = t; g < CH * CH / 8; g += blockDim.x) {
        int co  = g >> 4;            // output channel (row of Wt)
        int ci0 = (g & 15) * 8;      // 8 consecutive input channels
        unsigned int wbuf[4];
        #pragma unroll
        for (int h = 0; h < 4; ++h) {
            unsigned short lo = f2bf(wk[(size_t)(ci0 + 2*h)     * CH + co]);
            unsigned short hi = f2bf(wk[(size_t)(ci0 + 2*h + 1) * CH + co]);
            wbuf[h] = (unsigned)lo | ((unsigned)hi << 16);
        }
        *(uint4*)(wo + (size_t)co * CH + ci0) =
            make_uint4(wbuf[0], wbuf[1], wbuf[2], wbuf[3]);
    }
}

// K2: pipelined gather + MFMA over 27 offsets.
//  - A: single LDS buffer, chunk-rotated layout (conflict-free writes+reads).
//    Gathers (row-contiguous, 16 lanes = one 256B row) issued one k ahead
//    into G[8] VGPRs, hidden under the MFMA phase of k.
//  - B: single LDS buffer staged via global_load_lds (16B, contiguous,
//    zero VGPR cost, no line amplification).
//  - 2 barriers per k, 2 blocks/CU; no register double-buffers -> no spill.
__global__ __launch_bounds__(256, 2) void conv_mfma(
        const unsigned short* __restrict__ feat,   // [N][128] bf16
        const int* __restrict__ nbr,               // [27][N]
        const unsigned short* __restrict__ Wt,     // [27][cout][cin] bf16
        const unsigned short* __restrict__ zpage,  // 256 B of zeros
        float* __restrict__ out,                   // [N][128] conv result
        float* __restrict__ stats) {               // sums[128], sumsq[128]
    __shared__ __bf16 As[TM * CH];                 // 32 KB, rotated chunks
    __shared__ __bf16 Bs[CH * CH];                 // 32 KB, row-major
    __shared__ int idxL[NOFF * TM];                // 13,824 B (reused as sred)

    const int t    = threadIdx.x;
    const int row0 = blockIdx.x * TM;
    const int wid  = t >> 6;
    const int lane = t & 63;
    const int wr   = (wid >> 1) * 64;   // wave row offset in tile
    const int wc   = (wid & 1) * 64;    // wave col offset in tile
    const int lr   = lane & 15;
    const int quad = lane >> 4;

    // ---- stage the whole neighbor-index table once (coalesced)
    for (int e = t; e < NOFF * TM; e += 256) {
        int k = e >> 7, r = e & 127;
        int gr = row0 + r;
        idxL[e] = (gr < N_ACT) ? nbr[(size_t)k * N_ACT + gr] : -1;
    }
    __syncthreads();

    v4f acc[4][4];
    #pragma unroll
    for (int i = 0; i < 4; ++i)
        #pragma unroll
        for (int j = 0; j < 4; ++j)
            acc[i][j] = (v4f){0.f, 0.f, 0.f, 0.f};

    // staging coords: thread t gathers chunk sc (16B) of rows p*16+sr0
    const int sc  = t & 15;
    const int sr0 = t >> 4;
    const unsigned short* zsrc = zpage + sc * 8;

    uint4 G[8];          // gathered A rows in flight (only persistent regs)

    auto issueG = [&](int k) {
        #pragma unroll
        for (int p = 0; p < 8; ++p) {
            int idx = idxL[k * TM + p * 16 + sr0];
            const unsigned short* src =
                (idx >= 0) ? feat + ((size_t)idx << 7) + sc * 8 : zsrc;
            G[p] = *(const uint4*)src;
        }
    };
    // rotated-chunk A store: addr = row*128 + ((sc+row)&15)*8
    auto writeG = [&]() {
        #pragma unroll
        for (int p = 0; p < 8; ++p) {
            int row = p * 16 + sr0;
            *(uint4*)(As + row * CH + (((sc + row) & 15) << 3)) = G[p];
        }
    };
    auto dmaB = [&](int k) {
        const unsigned short* wk = Wt + (size_t)k * CH * CH;
        #pragma unroll
        for (int c = 0; c < 8; ++c) {
            int seg = wid * 8 + c;                 // 1 KB segment
            __builtin_amdgcn_global_load_lds(
                (const __attribute__((address_space(1))) unsigned int*)
                    (wk + seg * 512 + lane * 8),
                (__attribute__((address_space(3))) unsigned int*)(Bs + seg * 512),
                16, 0, 0);
        }
    };
    auto mfmaPhase = [&]() {
        #pragma unroll
        for (int kk = 0; kk < 4; ++kk) {
            v8bf a[4], b[4];
            #pragma unroll
            for (int i = 0; i < 4; ++i) {
                int row = wr + i * 16 + lr;
                a[i] = *(const v8bf*)(As + row * CH
                                      + (((kk * 4 + quad + row) & 15) << 3));
            }
            #pragma unroll
            for (int j = 0; j < 4; ++j)
                b[j] = *(const v8bf*)(Bs + (wc + j * 16 + lr) * CH
                                      + kk * 32 + quad * 8);
            #pragma unroll
            for (int i = 0; i < 4; ++i)
                #pragma unroll
                for (int j = 0; j < 4; ++j)
                    acc[i][j] = __builtin_amdgcn_mfma_f32_16x16x32_bf16(
                        a[i], b[j], acc[i][j], 0, 0, 0);
        }
    };

    // ---- prologue: stage tile 0
    issueG(0);
    dmaB(0);
    writeG();
    __syncthreads();

    // ---- pipelined k-loop (keep code small: no outer unroll)
    #pragma unroll 1
    for (int k = 0; k < NOFF; ++k) {
        if (k + 1 < NOFF) issueG(k + 1);   // hidden under MFMA phase
        mfmaPhase();
        if (k + 1 < NOFF) {
            __syncthreads();               // As/Bs consumed
            dmaB(k + 1);
            writeG();                      // G(k+1) landed during MFMA
            __syncthreads();               // stage complete (drains DMA)
        }
    }

    // ---- epilogue: store conv result + per-column partial stats
    float psum[4] = {0.f, 0.f, 0.f, 0.f};
    float psq[4]  = {0.f, 0.f, 0.f, 0.f};
    #pragma unroll
    for (int i = 0; i < 4; ++i) {
        #pragma unroll
        for (int r = 0; r < 4; ++r) {
            int grow = row0 + wr + i * 16 + quad * 4 + r;
            if (grow < N_ACT) {
                #pragma unroll
                for (int j = 0; j < 4; ++j) {
                    float v = acc[i][j][r];
                    out[(size_t)grow * CH + wc + j * 16 + lr] = v;
                    psum[j] += v;
                    psq[j]  += v * v;
                }
            }
        }
    }
    #pragma unroll
    for (int j = 0; j < 4; ++j) {
        psum[j] += __shfl_xor(psum[j], 16, 64);
        psq[j]  += __shfl_xor(psq[j], 16, 64);
        psum[j] += __shfl_xor(psum[j], 32, 64);
        psq[j]  += __shfl_xor(psq[j], 32, 64);
    }
    // reuse idxL as reduction scratch (idx reads all done)
    float* sred = (float*)idxL;   // [0..255]=sum[c][half], [256..511]=sq
    __syncthreads();
    if (quad == 0) {
        #pragma unroll
        for (int j = 0; j < 4; ++j) {
            int c = wc + j * 16 + lr;
            sred[c * 2 + (wid >> 1)]       = psum[j];
            sred[256 + c * 2 + (wid >> 1)] = psq[j];
        }
    }
    __syncthreads();
    if (t < CH) {
        atomicAdd(&stats[t],      sred[t * 2] + sred[t * 2 + 1]);
        atomicAdd(&stats[CH + t], sred[256 + t * 2] + sred[256 + t * 2 + 1]);
    }
}

// K3: per-channel scale/shift from batch stats
__global__ void finalize_stats(const float* __restrict__ gamma,
                               const float* __restrict__ beta,
                               float* __restrict__ stats) {
    int c = threadIdx.x;
    if (c < CH) {
        float inv_n = 1.0f / (float)N_ACT;
        float mean  = stats[c] * inv_n;
        float var   = stats[CH + c] * inv_n - mean * mean;
        float sc    = gamma[c] * rsqrtf(var + 1e-4f);
        stats[2 * CH + c] = sc;
        stats[3 * CH + c] = beta[c] - mean * sc;
    }
}

// K4: out = relu(conv * scale[c] + shift[c]), float4
__global__ void bn_relu(const float* __restrict__ conv,
                        const float* __restrict__ stats,
                        float* __restrict__ out) {
    long long i = (long long)blockIdx.x * blockDim.x + threadIdx.x;
    if (i >= (long long)N_ACT * CH / 4) return;
    int c4 = (int)(i & 31) * 4;
    float4 v  = ((const float4*)conv)[i];
    float4 sc = *(const float4*)(stats + 2 * CH + c4);
    float4 sh = *(const float4*)(stats + 3 * CH + c4);
    float4 o;
    o.x = fmaxf(v.x * sc.x + sh.x, 0.f);
    o.y = fmaxf(v.y * sc.y + sh.y, 0.f);
    o.z = fmaxf(v.z * sc.z + sh.z, 0.f);
    o.w = fmaxf(v.w * sc.w + sh.w, 0.f);
    ((float4*)out)[i] = o;
}

extern "C" void kernel_launch(void* const* d_in, const int* in_sizes, int n_in,
                              void* d_out, int out_size, void* d_ws, size_t ws_size,
                              hipStream_t stream) {
    const float* features = (const float*)d_in[0];
    const int*   nbr      = (const int*)d_in[1];
    const float* W        = (const float*)d_in[2];
    const float* gamma    = (const float*)d_in[3];
    const float* beta     = (const float*)d_in[4];
    float* outp = (float*)d_out;

    char* ws = (char*)d_ws;
    // layout: feat_bf16 (51,200,000 B) | Wt (884,736 B) | conv fp32
    // (102,400,000 B) | stats (512 floats) | zero page (256 B)
    unsigned short* feat_bf = (unsigned short*)ws;
    unsigned short* Wt      = (unsigned short*)(ws + 51200000);
    float* conv             = (float*)(ws + 51200000 + 884736);
    float* stats            = (float*)(ws + 51200000 + 884736 + 102400000);
    float* zpage            = stats + 4 * CH;

    cast_feat<<<12500, 256, 0, stream>>>(features, feat_bf);
    prep_w<<<NOFF, 256, 0, stream>>>(W, Wt, stats, zpage);
    conv_mfma<<<(N_ACT + TM - 1) / TM, 256, 0, stream>>>(
        feat_bf, nbr, Wt, (const unsigned short*)zpage, conv, stats);
    finalize_stats<<<1, CH, 0, stream>>>(gamma, beta, stats);
    bn_relu<<<25000, 256, 0, stream>>>(conv, stats, outp);
}

// Round 5
// 732.149 us; speedup vs baseline: 1.2395x; 1.0541x over previous
//
#include <hip/hip_runtime.h>
#include <hip/hip_bf16.h>
#include <cstdint>
#include <cstddef>

#define N_ACT 200000
#define CH 128
#define NOFF 27
#define TM 128

typedef __bf16 v8bf __attribute__((ext_vector_type(8)));
typedef float v4f __attribute__((ext_vector_type(4)));

__device__ __forceinline__ unsigned short f2bf(float f) {
    union { float f; unsigned int u; } x; x.f = f;
    unsigned int lsb = (x.u >> 16) & 1u;
    x.u += 0x7fffu + lsb;            // round-to-nearest-even
    return (unsigned short)(x.u >> 16);
}

// K1a: cast features fp32 -> bf16, 8 elements/thread
__global__ void cast_feat(const float* __restrict__ in,
                          unsigned short* __restrict__ out) {
    long long i = (long long)blockIdx.x * blockDim.x + threadIdx.x;
    long long base = i * 8;
    if (base >= (long long)N_ACT * CH) return;
    const float4* p = (const float4*)(in + base);
    float4 a = p[0], b = p[1];
    unsigned int w0 = (unsigned)f2bf(a.x) | ((unsigned)f2bf(a.y) << 16);
    unsigned int w1 = (unsigned)f2bf(a.z) | ((unsigned)f2bf(a.w) << 16);
    unsigned int w2 = (unsigned)f2bf(b.x) | ((unsigned)f2bf(b.y) << 16);
    unsigned int w3 = (unsigned)f2bf(b.z) | ((unsigned)f2bf(b.w) << 16);
    *(uint4*)(out + base) = make_uint4(w0, w1, w2, w3);
}

// K1b: W[k][cin][cout] fp32 -> Wt[k][cout][cin] bf16; block 0 zeros stats+zpage
__global__ void prep_w(const float* __restrict__ W,
                       unsigned short* __restrict__ Wt,
                       float* __restrict__ stats,
                       float* __restrict__ zpage) {
    int k = blockIdx.x;
    int t = threadIdx.x;
    if (k == 0 && t < 2 * CH) stats[t] = 0.0f;   // sums + sumsq
    if (k == 0 && t < 64) zpage[t] = 0.0f;       // 256 B zero row for gathers
    const float* wk = W + (size_t)k * CH * CH;
    unsigned short* wo = Wt + (size_t)k * CH * CH;
    for (int g = t; g < CH * CH / 8; g += blockDim.x) {
        int co  = g >> 4;            // output channel (row of Wt)
        int ci0 = (g & 15) * 8;      // 8 consecutive input channels
        unsigned int wbuf[4];
        #pragma unroll
        for (int h = 0; h < 4; ++h) {
            unsigned short lo = f2bf(wk[(size_t)(ci0 + 2*h)     * CH + co]);
            unsigned short hi = f2bf(wk[(size_t)(ci0 + 2*h + 1) * CH + co]);
            wbuf[h] = (unsigned)lo | ((unsigned)hi << 16);
        }
        *(uint4*)(wo + (size_t)co * CH + ci0) =
            make_uint4(wbuf[0], wbuf[1], wbuf[2], wbuf[3]);
    }
}

// K2: barrier-free direct-gather MFMA.
// Each wave owns a 64x64 output tile. A-fragments are gathered straight
// from the (L2/L3-resident) feature rows into MFMA A-registers (16B/lane,
// contiguous per row); B-fragments straight from L2-resident Wt. No LDS
// in the main loop, no __syncthreads, no global_load_lds.
__global__ __launch_bounds__(256, 2) void conv_mfma(
        const unsigned short* __restrict__ feat,   // [N][128] bf16
        const int* __restrict__ nbr,               // [27][N]
        const unsigned short* __restrict__ Wt,     // [27][cout][cin] bf16
        const unsigned short* __restrict__ zpage,  // 256 B of zeros
        float* __restrict__ out,                   // [N][128] conv result
        float* __restrict__ stats) {               // sums[128], sumsq[128]
    __shared__ float sred[512];                    // 2 KB (epilogue only)

    const int t    = threadIdx.x;
    const int row0 = blockIdx.x * TM;
    const int wid  = t >> 6;
    const int lane = t & 63;
    const int wr   = (wid >> 1) * 64;   // wave row offset in tile
    const int wc   = (wid & 1) * 64;    // wave col offset in tile
    const int lr   = lane & 15;
    const int quad = lane >> 4;

    // clamped neighbor-table row per i-subtile (OOB rows read row 0's entry;
    // their acc values are discarded by the grow<N_ACT guards below)
    int rbase[4];
    #pragma unroll
    for (int i = 0; i < 4; ++i) {
        int r = row0 + wr + i * 16 + lr;
        rbase[i] = (r < N_ACT) ? r : 0;
    }

    v4f acc[4][4];
    #pragma unroll
    for (int i = 0; i < 4; ++i)
        #pragma unroll
        for (int j = 0; j < 4; ++j)
            acc[i][j] = (v4f){0.f, 0.f, 0.f, 0.f};

    const size_t qoff = (size_t)(quad * 8);   // elems: lane's 16B chunk in K

    int idxc[4], idxn[4];
    #pragma unroll
    for (int i = 0; i < 4; ++i) idxc[i] = nbr[rbase[i]];   // k = 0

    #pragma unroll 1
    for (int k = 0; k < NOFF; ++k) {
        // per-i source row pointers (zpage when neighbor inactive)
        const unsigned short* s0 =
            (idxc[0] >= 0 ? feat + ((size_t)idxc[0] << 7) : zpage) + qoff;
        const unsigned short* s1 =
            (idxc[1] >= 0 ? feat + ((size_t)idxc[1] << 7) : zpage) + qoff;
        const unsigned short* s2 =
            (idxc[2] >= 0 ? feat + ((size_t)idxc[2] << 7) : zpage) + qoff;
        const unsigned short* s3 =
            (idxc[3] >= 0 ? feat + ((size_t)idxc[3] << 7) : zpage) + qoff;

        // A fragments: 16 direct gathers (issue all, consume kk-major)
        v8bf a[4][4];
        #pragma unroll
        for (int kk = 0; kk < 4; ++kk) {
            a[kk][0] = *(const v8bf*)(s0 + kk * 32);
            a[kk][1] = *(const v8bf*)(s1 + kk * 32);
            a[kk][2] = *(const v8bf*)(s2 + kk * 32);
            a[kk][3] = *(const v8bf*)(s3 + kk * 32);
        }
        // B fragments: 16 loads from L2-resident Wt
        const unsigned short* wb = Wt + (size_t)k * CH * CH
                                 + (size_t)(wc + lr) * CH + qoff;
        v8bf b[4][4];
        #pragma unroll
        for (int kk = 0; kk < 4; ++kk)
            #pragma unroll
            for (int j = 0; j < 4; ++j)
                b[kk][j] = *(const v8bf*)(wb + (size_t)(j * 16) * CH + kk * 32);
        // neighbor indices for k+1 ride out the MFMA phase in the queue
        if (k + 1 < NOFF) {
            const int* nb = nbr + (size_t)(k + 1) * N_ACT;
            #pragma unroll
            for (int i = 0; i < 4; ++i) idxn[i] = nb[rbase[i]];
        }
        // MFMA phase
        #pragma unroll
        for (int kk = 0; kk < 4; ++kk)
            #pragma unroll
            for (int i = 0; i < 4; ++i)
                #pragma unroll
                for (int j = 0; j < 4; ++j)
                    acc[i][j] = __builtin_amdgcn_mfma_f32_16x16x32_bf16(
                        a[kk][i], b[kk][j], acc[i][j], 0, 0, 0);
        #pragma unroll
        for (int i = 0; i < 4; ++i) idxc[i] = idxn[i];
    }

    // ---- epilogue: store conv result + per-column partial stats
    float psum[4] = {0.f, 0.f, 0.f, 0.f};
    float psq[4]  = {0.f, 0.f, 0.f, 0.f};
    #pragma unroll
    for (int i = 0; i < 4; ++i) {
        #pragma unroll
        for (int r = 0; r < 4; ++r) {
            int grow = row0 + wr + i * 16 + quad * 4 + r;
            if (grow < N_ACT) {
                #pragma unroll
                for (int j = 0; j < 4; ++j) {
                    float v = acc[i][j][r];
                    out[(size_t)grow * CH + wc + j * 16 + lr] = v;
                    psum[j] += v;
                    psq[j]  += v * v;
                }
            }
        }
    }
    #pragma unroll
    for (int j = 0; j < 4; ++j) {
        psum[j] += __shfl_xor(psum[j], 16, 64);
        psq[j]  += __shfl_xor(psq[j], 16, 64);
        psum[j] += __shfl_xor(psum[j], 32, 64);
        psq[j]  += __shfl_xor(psq[j], 32, 64);
    }
    if (quad == 0) {
        #pragma unroll
        for (int j = 0; j < 4; ++j) {
            int c = wc + j * 16 + lr;
            sred[c * 2 + (wid >> 1)]       = psum[j];
            sred[256 + c * 2 + (wid >> 1)] = psq[j];
        }
    }
    __syncthreads();
    if (t < CH) {
        atomicAdd(&stats[t],      sred[t * 2] + sred[t * 2 + 1]);
        atomicAdd(&stats[CH + t], sred[256 + t * 2] + sred[256 + t * 2 + 1]);
    }
}

// K3: per-channel scale/shift from batch stats
__global__ void finalize_stats(const float* __restrict__ gamma,
                               const float* __restrict__ beta,
                               float* __restrict__ stats) {
    int c = threadIdx.x;
    if (c < CH) {
        float inv_n = 1.0f / (float)N_ACT;
        float mean  = stats[c] * inv_n;
        float var   = stats[CH + c] * inv_n - mean * mean;
        float sc    = gamma[c] * rsqrtf(var + 1e-4f);
        stats[2 * CH + c] = sc;
        stats[3 * CH + c] = beta[c] - mean * sc;
    }
}

// K4: out = relu(conv * scale[c] + shift[c]), float4
__global__ void bn_relu(const float* __restrict__ conv,
                        const float* __restrict__ stats,
                        float* __restrict__ out) {
    long long i = (long long)blockIdx.x * blockDim.x + threadIdx.x;
    if (i >= (long long)N_ACT * CH / 4) return;
    int c4 = (int)(i & 31) * 4;
    float4 v  = ((const float4*)conv)[i];
    float4 sc = *(const float4*)(stats + 2 * CH + c4);
    float4 sh = *(const float4*)(stats + 3 * CH + c4);
    float4 o;
    o.x = fmaxf(v.x * sc.x + sh.x, 0.f);
    o.y = fmaxf(v.y * sc.y + sh.y, 0.f);
    o.z = fmaxf(v.z * sc.z + sh.z, 0.f);
    o.w = fmaxf(v.w * sc.w + sh.w, 0.f);
    ((float4*)out)[i] = o;
}

extern "C" void kernel_launch(void* const* d_in, const int* in_sizes, int n_in,
                              void* d_out, int out_size, void* d_ws, size_t ws_size,
                              hipStream_t stream) {
    const float* features = (const float*)d_in[0];
    const int*   nbr      = (const int*)d_in[1];
    const float* W        = (const float*)d_in[2];
    const float* gamma    = (const float*)d_in[3];
    const float* beta     = (const float*)d_in[4];
    float* outp = (float*)d_out;

    char* ws = (char*)d_ws;
    // layout: feat_bf16 (51,200,000 B) | Wt (884,736 B) | conv fp32
    // (102,400,000 B) | stats (512 floats) | zero page (256 B)
    unsigned short* feat_bf = (unsigned short*)ws;
    unsigned short* Wt      = (unsigned short*)(ws + 51200000);
    float* conv             = (float*)(ws + 51200000 + 884736);
    float* stats            = (float*)(ws + 51200000 + 884736 + 102400000);
    float* zpage            = stats + 4 * CH;

    cast_feat<<<12500, 256, 0, stream>>>(features, feat_bf);
    prep_w<<<NOFF, 256, 0, stream>>>(W, Wt, stats, zpage);
    conv_mfma<<<(N_ACT + TM - 1) / TM, 256, 0, stream>>>(
        feat_bf, nbr, Wt, (const unsigned short*)zpage, conv, stats);
    finalize_stats<<<1, CH, 0, stream>>>(gamma, beta, stats);
    bn_relu<<<25000, 256, 0, stream>>>(conv, stats, outp);
}

// Round 6
// 723.442 us; speedup vs baseline: 1.2545x; 1.0120x over previous
//
#include <hip/hip_runtime.h>
#include <hip/hip_bf16.h>
#include <cstdint>
#include <cstddef>

#define N_ACT 200000
#define CH 128
#define NOFF 27
#define TM 128

typedef __bf16 v8bf __attribute__((ext_vector_type(8)));
typedef float v4f __attribute__((ext_vector_type(4)));

__device__ __forceinline__ unsigned short f2bf(float f) {
    union { float f; unsigned int u; } x; x.f = f;
    unsigned int lsb = (x.u >> 16) & 1u;
    x.u += 0x7fffu + lsb;            // round-to-nearest-even
    return (unsigned short)(x.u >> 16);
}

// K1a: cast features fp32 -> bf16, 8 elements/thread
__global__ void cast_feat(const float* __restrict__ in,
                          unsigned short* __restrict__ out) {
    long long i = (long long)blockIdx.x * blockDim.x + threadIdx.x;
    long long base = i * 8;
    if (base >= (long long)N_ACT * CH) return;
    const float4* p = (const float4*)(in + base);
    float4 a = p[0], b = p[1];
    unsigned int w0 = (unsigned)f2bf(a.x) | ((unsigned)f2bf(a.y) << 16);
    unsigned int w1 = (unsigned)f2bf(a.z) | ((unsigned)f2bf(a.w) << 16);
    unsigned int w2 = (unsigned)f2bf(b.x) | ((unsigned)f2bf(b.y) << 16);
    unsigned int w3 = (unsigned)f2bf(b.z) | ((unsigned)f2bf(b.w) << 16);
    *(uint4*)(out + base) = make_uint4(w0, w1, w2, w3);
}

// K1b: pack W[k][cin][cout] fp32 into fragment-order bf16:
//   Wtp[(k*4+q)*4096 + (jkk*64 + lane)*8 + e]
// where q = col-quarter (wave id), jkk = j*4+kk (j<2, kk<4),
// lane = quad*16+lr, value = W[k][kk*32+quad*8+e][q*32+j*16+lr].
// A wave's 8 b-frag loads for one k are each 64 lanes x consecutive 16B.
__global__ void prep_w(const float* __restrict__ W,
                       unsigned short* __restrict__ Wtp,
                       float* __restrict__ stats,
                       float* __restrict__ zpage) {
    int k = blockIdx.x;
    int t = threadIdx.x;
    if (k == 0 && t < 2 * CH) stats[t] = 0.0f;   // sums + sumsq
    if (k == 0 && t < 64) zpage[t] = 0.0f;       // 256 B zero row for gathers
    const float* wk = W + (size_t)k * CH * CH;
    for (int g = t; g < 2048; g += 256) {
        int q = g >> 9, r = g & 511;
        int jkk = r >> 6, lane = r & 63;
        int j = jkk >> 2, kk = jkk & 3;
        int lr = lane & 15, quad = lane >> 4;
        int cout = q * 32 + j * 16 + lr;
        int cin0 = kk * 32 + quad * 8;
        unsigned int wbuf[4];
        #pragma unroll
        for (int h = 0; h < 4; ++h) {
            unsigned short lo = f2bf(wk[(size_t)(cin0 + 2*h)     * CH + cout]);
            unsigned short hi = f2bf(wk[(size_t)(cin0 + 2*h + 1) * CH + cout]);
            wbuf[h] = (unsigned)lo | ((unsigned)hi << 16);
        }
        *(uint4*)(Wtp + ((size_t)(k * 4 + q) << 12) + (size_t)(jkk * 64 + lane) * 8)
            = make_uint4(wbuf[0], wbuf[1], wbuf[2], wbuf[3]);
    }
}

// K2: LDS-double-buffered A + register-ping-pong packed B.
//  - A: row-contiguous gathers (16 lanes = one 256B row, 8 lines/instr)
//    -> G[8] regs -> ds_write into chunk-rotated As (conflict-free both ways).
//    Issued one k ahead; ages a full MFMA phase before ds_write.
//  - B: 8 fully-coalesced 1KB loads/wave from packed Wtp, prefetched one k
//    ahead into the alternate register set.
//  - Wave tile 128x32 (full A reuse from LDS, minimal B traffic).
__global__ __launch_bounds__(256, 2) void conv_mfma(
        const unsigned short* __restrict__ feat,   // [N][128] bf16
        const int* __restrict__ nbr,               // [27][N]
        const unsigned short* __restrict__ Wtp,    // packed (see prep_w)
        const unsigned short* __restrict__ zpage,  // 256 B of zeros
        float* __restrict__ out,                   // [N][128] conv result
        float* __restrict__ stats) {               // sums[128], sumsq[128]
    __shared__ __bf16 As0[TM * CH];                // 32 KB
    __shared__ __bf16 As1[TM * CH];                // 32 KB
    __shared__ int idxL[NOFF * TM];                // 13.8 KB
    __shared__ float sred[256];                    // 1 KB

    const int t    = threadIdx.x;
    const int row0 = blockIdx.x * TM;
    const int wid  = t >> 6;
    const int lane = t & 63;
    const int lr   = lane & 15;
    const int quad = lane >> 4;

    // ---- stage the whole neighbor-index table once (coalesced)
    for (int e = t; e < NOFF * TM; e += 256) {
        int k = e >> 7, r = e & 127;
        int gr = row0 + r;
        idxL[e] = (gr < N_ACT) ? nbr[(size_t)k * N_ACT + gr] : -1;
    }
    __syncthreads();

    v4f acc[8][2];
    #pragma unroll
    for (int i = 0; i < 8; ++i) {
        acc[i][0] = (v4f){0.f, 0.f, 0.f, 0.f};
        acc[i][1] = (v4f){0.f, 0.f, 0.f, 0.f};
    }

    // staging coords: thread t gathers chunk sc (16B) of rows p*16+sr0
    const int sc  = t & 15;
    const int sr0 = t >> 4;
    const unsigned short* zsrc = zpage + sc * 8;

    uint4 G[8];          // gathered A rows in flight
    v8bf B0[8], B1[8];   // B fragment ping-pong

    auto issueG = [&](int k) {
        #pragma unroll
        for (int p = 0; p < 8; ++p) {
            int row = p * 16 + sr0;
            int idx = idxL[k * TM + row];
            const unsigned short* src =
                (idx >= 0) ? feat + ((size_t)idx << 7) + sc * 8 : zsrc;
            G[p] = *(const uint4*)src;
        }
    };
    // rotated-chunk A store: slot ((sc+row)&15) of row
    auto writeG = [&](__bf16* buf) {
        #pragma unroll
        for (int p = 0; p < 8; ++p) {
            int row = p * 16 + sr0;
            *(uint4*)(buf + row * CH + (((sc + row) & 15) << 3)) = G[p];
        }
    };
    auto loadB = [&](int k, v8bf* dst) {
        const unsigned short* base =
            Wtp + ((size_t)(k * 4 + wid) << 12) + (size_t)lane * 8;
        #pragma unroll
        for (int jkk = 0; jkk < 8; ++jkk)
            dst[jkk] = *(const v8bf*)(base + jkk * 512);
    };
    auto mfmaPhase = [&](const __bf16* buf, const v8bf* b) {
        #pragma unroll
        for (int kk = 0; kk < 4; ++kk) {
            // chunk slot for this (kk,quad): ((kk*4+quad)+row)&15, and
            // row = i*16+lr with i*16 ≡ 0 mod 16 -> slot dep on lr only
            const int slot = ((kk * 4 + quad + lr) & 15) << 3;
            v8bf a[8];
            #pragma unroll
            for (int i = 0; i < 8; ++i)
                a[i] = *(const v8bf*)(buf + (i * 16 + lr) * CH + slot);
            #pragma unroll
            for (int i = 0; i < 8; ++i) {
                acc[i][0] = __builtin_amdgcn_mfma_f32_16x16x32_bf16(
                    a[i], b[kk], acc[i][0], 0, 0, 0);
                acc[i][1] = __builtin_amdgcn_mfma_f32_16x16x32_bf16(
                    a[i], b[4 + kk], acc[i][1], 0, 0, 0);
            }
        }
    };

    // ---- prologue: stage k=0
    issueG(0);
    loadB(0, B0);
    writeG(As0);
    __syncthreads();

    // ---- pipelined k-loop, x2 unrolled for literal ping-pong indices
    #pragma unroll 1
    for (int k = 0; k < NOFF; k += 2) {
        // even k: consume As0/B0
        if (k + 1 < NOFF) { issueG(k + 1); loadB(k + 1, B1); }
        mfmaPhase(As0, B0);
        if (k + 1 >= NOFF) break;
        writeG(As1);
        __syncthreads();
        // odd k+1: consume As1/B1
        if (k + 2 < NOFF) { issueG(k + 2); loadB(k + 2, B0); }
        mfmaPhase(As1, B1);
        if (k + 2 < NOFF) {
            writeG(As0);
            __syncthreads();
        }
    }

    // ---- epilogue: store conv result + per-column partial stats
    float psum[2] = {0.f, 0.f};
    float psq[2]  = {0.f, 0.f};
    #pragma unroll
    for (int i = 0; i < 8; ++i) {
        #pragma unroll
        for (int r = 0; r < 4; ++r) {
            int grow = row0 + i * 16 + quad * 4 + r;
            if (grow < N_ACT) {
                #pragma unroll
                for (int j = 0; j < 2; ++j) {
                    float v = acc[i][j][r];
                    out[(size_t)grow * CH + wid * 32 + j * 16 + lr] = v;
                    psum[j] += v;
                    psq[j]  += v * v;
                }
            }
        }
    }
    #pragma unroll
    for (int j = 0; j < 2; ++j) {
        psum[j] += __shfl_xor(psum[j], 16, 64);
        psq[j]  += __shfl_xor(psq[j], 16, 64);
        psum[j] += __shfl_xor(psum[j], 32, 64);
        psq[j]  += __shfl_xor(psq[j], 32, 64);
    }
    if (quad == 0) {
        #pragma unroll
        for (int j = 0; j < 2; ++j) {
            int c = wid * 32 + j * 16 + lr;
            sred[c]       = psum[j];
            sred[128 + c] = psq[j];
        }
    }
    __syncthreads();
    if (t < CH) {
        atomicAdd(&stats[t],      sred[t]);
        atomicAdd(&stats[CH + t], sred[128 + t]);
    }
}

// K3: per-channel scale/shift from batch stats
__global__ void finalize_stats(const float* __restrict__ gamma,
                               const float* __restrict__ beta,
                               float* __restrict__ stats) {
    int c = threadIdx.x;
    if (c < CH) {
        float inv_n = 1.0f / (float)N_ACT;
        float mean  = stats[c] * inv_n;
        float var   = stats[CH + c] * inv_n - mean * mean;
        float sc    = gamma[c] * rsqrtf(var + 1e-4f);
        stats[2 * CH + c] = sc;
        stats[3 * CH + c] = beta[c] - mean * sc;
    }
}

// K4: out = relu(conv * scale[c] + shift[c]), float4
__global__ void bn_relu(const float* __restrict__ conv,
                        const float* __restrict__ stats,
                        float* __restrict__ out) {
    long long i = (long long)blockIdx.x * blockDim.x + threadIdx.x;
    if (i >= (long long)N_ACT * CH / 4) return;
    int c4 = (int)(i & 31) * 4;
    float4 v  = ((const float4*)conv)[i];
    float4 sc = *(const float4*)(stats + 2 * CH + c4);
    float4 sh = *(const float4*)(stats + 3 * CH + c4);
    float4 o;
    o.x = fmaxf(v.x * sc.x + sh.x, 0.f);
    o.y = fmaxf(v.y * sc.y + sh.y, 0.f);
    o.z = fmaxf(v.z * sc.z + sh.z, 0.f);
    o.w = fmaxf(v.w * sc.w + sh.w, 0.f);
    ((float4*)out)[i] = o;
}

extern "C" void kernel_launch(void* const* d_in, const int* in_sizes, int n_in,
                              void* d_out, int out_size, void* d_ws, size_t ws_size,
                              hipStream_t stream) {
    const float* features = (const float*)d_in[0];
    const int*   nbr      = (const int*)d_in[1];
    const float* W        = (const float*)d_in[2];
    const float* gamma    = (const float*)d_in[3];
    const float* beta     = (const float*)d_in[4];
    float* outp = (float*)d_out;

    char* ws = (char*)d_ws;
    // layout: feat_bf16 (51,200,000 B) | Wtp (884,736 B) | conv fp32
    // (102,400,000 B) | stats (512 floats) | zero page (256 B)
    unsigned short* feat_bf = (unsigned short*)ws;
    unsigned short* Wtp     = (unsigned short*)(ws + 51200000);
    float* conv             = (float*)(ws + 51200000 + 884736);
    float* stats            = (float*)(ws + 51200000 + 884736 + 102400000);
    float* zpage            = stats + 4 * CH;

    cast_feat<<<12500, 256, 0, stream>>>(features, feat_bf);
    prep_w<<<NOFF, 256, 0, stream>>>(W, Wtp, stats, zpage);
    conv_mfma<<<(N_ACT + TM - 1) / TM, 256, 0, stream>>>(
        feat_bf, nbr, Wtp, (const unsigned short*)zpage, conv, stats);
    finalize_stats<<<1, CH, 0, stream>>>(gamma, beta, stats);
    bn_relu<<<25000, 256, 0, stream>>>(conv, stats, outp);
}

// Round 7
// 707.613 us; speedup vs baseline: 1.2825x; 1.0224x over previous
//
#include <hip/hip_runtime.h>
#include <hip/hip_bf16.h>
#include <cstdint>
#include <cstddef>

#define N_ACT 200000
#define CH 128
#define NOFF 27
#define TM 128

typedef __bf16 v8bf __attribute__((ext_vector_type(8)));
typedef float v4f __attribute__((ext_vector_type(4)));

__device__ __forceinline__ unsigned short f2bf(float f) {
    union { float f; unsigned int u; } x; x.f = f;
    unsigned int lsb = (x.u >> 16) & 1u;
    x.u += 0x7fffu + lsb;            // round-to-nearest-even
    return (unsigned short)(x.u >> 16);
}

// K1a: cast features fp32 -> bf16, 8 elements/thread
__global__ void cast_feat(const float* __restrict__ in,
                          unsigned short* __restrict__ out) {
    long long i = (long long)blockIdx.x * blockDim.x + threadIdx.x;
    long long base = i * 8;
    if (base >= (long long)N_ACT * CH) return;
    const float4* p = (const float4*)(in + base);
    float4 a = p[0], b = p[1];
    unsigned int w0 = (unsigned)f2bf(a.x) | ((unsigned)f2bf(a.y) << 16);
    unsigned int w1 = (unsigned)f2bf(a.z) | ((unsigned)f2bf(a.w) << 16);
    unsigned int w2 = (unsigned)f2bf(b.x) | ((unsigned)f2bf(b.y) << 16);
    unsigned int w3 = (unsigned)f2bf(b.z) | ((unsigned)f2bf(b.w) << 16);
    *(uint4*)(out + base) = make_uint4(w0, w1, w2, w3);
}

// K1b: pack W[k][cin][cout] fp32 into fragment-order bf16:
//   Wtp[(k*4+q)*4096 + (jkk*64 + lane)*8 + e]
// q = col-quarter (wave id), jkk = j*4+kk, lane = quad*16+lr,
// value = W[k][kk*32+quad*8+e][q*32+j*16+lr].
// -> each wave's 8 b-frag loads per k are 64 lanes x consecutive 16B (1 KB).
__global__ void prep_w(const float* __restrict__ W,
                       unsigned short* __restrict__ Wtp,
                       float* __restrict__ stats,
                       float* __restrict__ zpage) {
    int k = blockIdx.x;
    int t = threadIdx.x;
    if (k == 0 && t < 2 * CH) stats[t] = 0.0f;   // sums + sumsq
    if (k == 0 && t < 64) zpage[t] = 0.0f;       // 256 B zero row for gathers
    const float* wk = W + (size_t)k * CH * CH;
    for (int g = t; g < 2048; g += 256) {
        int q = g >> 9, r = g & 511;
        int jkk = r >> 6, lane = r & 63;
        int j = jkk >> 2, kk = jkk & 3;
        int lr = lane & 15, quad = lane >> 4;
        int cout = q * 32 + j * 16 + lr;
        int cin0 = kk * 32 + quad * 8;
        unsigned int wbuf[4];
        #pragma unroll
        for (int h = 0; h < 4; ++h) {
            unsigned short lo = f2bf(wk[(size_t)(cin0 + 2*h)     * CH + cout]);
            unsigned short hi = f2bf(wk[(size_t)(cin0 + 2*h + 1) * CH + cout]);
            wbuf[h] = (unsigned)lo | ((unsigned)hi << 16);
        }
        *(uint4*)(Wtp + ((size_t)(k * 4 + q) << 12) + (size_t)(jkk * 64 + lane) * 8)
            = make_uint4(wbuf[0], wbuf[1], wbuf[2], wbuf[3]);
    }
}

// K2: LDS-double-buffered A, single-set register B, one barrier per k.
// Register budget held ~170 (acc 64 + G 32 + B 32 + a 16 + addr) -> no spill.
__global__ __launch_bounds__(256, 2) void conv_mfma(
        const unsigned short* __restrict__ feat,   // [N][128] bf16
        const int* __restrict__ nbr,               // [27][N]
        const unsigned short* __restrict__ Wtp,    // packed (see prep_w)
        const unsigned short* __restrict__ zpage,  // 256 B of zeros
        float* __restrict__ out,                   // [N][128] conv result
        float* __restrict__ stats) {               // sums[128], sumsq[128]
    __shared__ __bf16 As0[TM * CH];                // 32 KB
    __shared__ __bf16 As1[TM * CH];                // 32 KB
    __shared__ int idxL[NOFF * TM];                // 13.8 KB
    __shared__ float sred[256];                    // 1 KB

    const int t    = threadIdx.x;
    const int row0 = blockIdx.x * TM;
    const int wid  = t >> 6;
    const int lane = t & 63;
    const int lr   = lane & 15;
    const int quad = lane >> 4;

    // ---- stage the whole neighbor-index table once (coalesced)
    for (int e = t; e < NOFF * TM; e += 256) {
        int k = e >> 7, r = e & 127;
        int gr = row0 + r;
        idxL[e] = (gr < N_ACT) ? nbr[(size_t)k * N_ACT + gr] : -1;
    }
    __syncthreads();

    v4f acc[8][2];
    #pragma unroll
    for (int i = 0; i < 8; ++i) {
        acc[i][0] = (v4f){0.f, 0.f, 0.f, 0.f};
        acc[i][1] = (v4f){0.f, 0.f, 0.f, 0.f};
    }

    // staging coords: thread t gathers chunk sc (16B) of rows p*16+sr0
    const int sc  = t & 15;
    const int sr0 = t >> 4;
    const unsigned short* zsrc = zpage + sc * 8;

    uint4 G[8];          // gathered A rows in flight
    v8bf B[8];           // single B fragment set

    auto issueG = [&](int k) {
        #pragma unroll
        for (int p = 0; p < 8; ++p) {
            int row = p * 16 + sr0;
            int idx = idxL[k * TM + row];
            const unsigned short* src =
                (idx >= 0) ? feat + ((size_t)idx << 7) + sc * 8 : zsrc;
            G[p] = *(const uint4*)src;
        }
    };
    // rotated-chunk A store: slot ((sc+row)&15) of row
    auto writeG = [&](__bf16* buf) {
        #pragma unroll
        for (int p = 0; p < 8; ++p) {
            int row = p * 16 + sr0;
            *(uint4*)(buf + row * CH + (((sc + row) & 15) << 3)) = G[p];
        }
    };
    auto loadB = [&](int k) {
        const unsigned short* base =
            Wtp + ((size_t)(k * 4 + wid) << 12) + (size_t)lane * 8;
        #pragma unroll
        for (int jkk = 0; jkk < 8; ++jkk)
            B[jkk] = *(const v8bf*)(base + jkk * 512);
    };
    // i-blocked: per row-subtile load 4 a-frags (16 regs), fire 8 MFMAs
    auto mfmaPhase = [&](const __bf16* buf) {
        #pragma unroll
        for (int i = 0; i < 8; ++i) {
            const __bf16* rowp = buf + (i * 16 + lr) * CH;
            v8bf a[4];
            #pragma unroll
            for (int kk = 0; kk < 4; ++kk)
                a[kk] = *(const v8bf*)(rowp + (((kk * 4 + quad + lr) & 15) << 3));
            #pragma unroll
            for (int kk = 0; kk < 4; ++kk) {
                acc[i][0] = __builtin_amdgcn_mfma_f32_16x16x32_bf16(
                    a[kk], B[kk], acc[i][0], 0, 0, 0);
                acc[i][1] = __builtin_amdgcn_mfma_f32_16x16x32_bf16(
                    a[kk], B[4 + kk], acc[i][1], 0, 0, 0);
            }
        }
    };

    // ---- prologue: stage A(0)
    issueG(0);
    writeG(As0);
    __syncthreads();

    // ---- pipelined k-loop, x2 unrolled for literal buffer names.
    // Order matters: loadB(k) BEFORE issueG(k+1) so the B-wait is
    // vmcnt(8) (G still in flight), and writeG after the phase drains G.
    #pragma unroll 1
    for (int k = 0; k < NOFF; k += 2) {
        loadB(k);
        if (k + 1 < NOFF) issueG(k + 1);
        mfmaPhase(As0);
        if (k + 1 >= NOFF) break;
        writeG(As1);
        __syncthreads();

        loadB(k + 1);
        if (k + 2 < NOFF) issueG(k + 2);
        mfmaPhase(As1);
        if (k + 2 >= NOFF) break;
        writeG(As0);
        __syncthreads();
    }

    // ---- epilogue: store conv result + per-column partial stats
    float psum[2] = {0.f, 0.f};
    float psq[2]  = {0.f, 0.f};
    #pragma unroll
    for (int i = 0; i < 8; ++i) {
        #pragma unroll
        for (int r = 0; r < 4; ++r) {
            int grow = row0 + i * 16 + quad * 4 + r;
            if (grow < N_ACT) {
                #pragma unroll
                for (int j = 0; j < 2; ++j) {
                    float v = acc[i][j][r];
                    out[(size_t)grow * CH + wid * 32 + j * 16 + lr] = v;
                    psum[j] += v;
                    psq[j]  += v * v;
                }
            }
        }
    }
    #pragma unroll
    for (int j = 0; j < 2; ++j) {
        psum[j] += __shfl_xor(psum[j], 16, 64);
        psq[j]  += __shfl_xor(psq[j], 16, 64);
        psum[j] += __shfl_xor(psum[j], 32, 64);
        psq[j]  += __shfl_xor(psq[j], 32, 64);
    }
    if (quad == 0) {
        #pragma unroll
        for (int j = 0; j < 2; ++j) {
            int c = wid * 32 + j * 16 + lr;
            sred[c]       = psum[j];
            sred[128 + c] = psq[j];
        }
    }
    __syncthreads();
    if (t < CH) {
        atomicAdd(&stats[t],      sred[t]);
        atomicAdd(&stats[CH + t], sred[128 + t]);
    }
}

// K3: per-channel scale/shift from batch stats
__global__ void finalize_stats(const float* __restrict__ gamma,
                               const float* __restrict__ beta,
                               float* __restrict__ stats) {
    int c = threadIdx.x;
    if (c < CH) {
        float inv_n = 1.0f / (float)N_ACT;
        float mean  = stats[c] * inv_n;
        float var   = stats[CH + c] * inv_n - mean * mean;
        float sc    = gamma[c] * rsqrtf(var + 1e-4f);
        stats[2 * CH + c] = sc;
        stats[3 * CH + c] = beta[c] - mean * sc;
    }
}

// K4: out = relu(conv * scale[c] + shift[c]), float4
__global__ void bn_relu(const float* __restrict__ conv,
                        const float* __restrict__ stats,
                        float* __restrict__ out) {
    long long i = (long long)blockIdx.x * blockDim.x + threadIdx.x;
    if (i >= (long long)N_ACT * CH / 4) return;
    int c4 = (int)(i & 31) * 4;
    float4 v  = ((const float4*)conv)[i];
    float4 sc = *(const float4*)(stats + 2 * CH + c4);
    float4 sh = *(const float4*)(stats + 3 * CH + c4);
    float4 o;
    o.x = fmaxf(v.x * sc.x + sh.x, 0.f);
    o.y = fmaxf(v.y * sc.y + sh.y, 0.f);
    o.z = fmaxf(v.z * sc.z + sh.z, 0.f);
    o.w = fmaxf(v.w * sc.w + sh.w, 0.f);
    ((float4*)out)[i] = o;
}

extern "C" void kernel_launch(void* const* d_in, const int* in_sizes, int n_in,
                              void* d_out, int out_size, void* d_ws, size_t ws_size,
                              hipStream_t stream) {
    const float* features = (const float*)d_in[0];
    const int*   nbr      = (const int*)d_in[1];
    const float* W        = (const float*)d_in[2];
    const float* gamma    = (const float*)d_in[3];
    const float* beta     = (const float*)d_in[4];
    float* outp = (float*)d_out;

    char* ws = (char*)d_ws;
    // layout: feat_bf16 (51,200,000 B) | Wtp (884,736 B) | conv fp32
    // (102,400,000 B) | stats (512 floats) | zero page (256 B)
    unsigned short* feat_bf = (unsigned short*)ws;
    unsigned short* Wtp     = (unsigned short*)(ws + 51200000);
    float* conv             = (float*)(ws + 51200000 + 884736);
    float* stats            = (float*)(ws + 51200000 + 884736 + 102400000);
    float* zpage            = stats + 4 * CH;

    cast_feat<<<12500, 256, 0, stream>>>(features, feat_bf);
    prep_w<<<NOFF, 256, 0, stream>>>(W, Wtp, stats, zpage);
    conv_mfma<<<(N_ACT + TM - 1) / TM, 256, 0, stream>>>(
        feat_bf, nbr, Wtp, (const unsigned short*)zpage, conv, stats);
    finalize_stats<<<1, CH, 0, stream>>>(gamma, beta, stats);
    bn_relu<<<25000, 256, 0, stream>>>(conv, stats, outp);
}

// Round 8
// 405.840 us; speedup vs baseline: 2.2362x; 1.7436x over previous
//
#include <hip/hip_runtime.h>
#include <hip/hip_bf16.h>
#include <cstdint>
#include <cstddef>

#define N_ACT 200000
#define CH 128
#define NOFF 27
#define TM 128

typedef __bf16 v8bf __attribute__((ext_vector_type(8)));
typedef float v4f __attribute__((ext_vector_type(4)));

__device__ __forceinline__ unsigned short f2bf(float f) {
    union { float f; unsigned int u; } x; x.f = f;
    unsigned int lsb = (x.u >> 16) & 1u;
    x.u += 0x7fffu + lsb;            // round-to-nearest-even
    return (unsigned short)(x.u >> 16);
}

// K1a: cast features fp32 -> bf16, 8 elements/thread
__global__ void cast_feat(const float* __restrict__ in,
                          unsigned short* __restrict__ out) {
    long long i = (long long)blockIdx.x * blockDim.x + threadIdx.x;
    long long base = i * 8;
    if (base >= (long long)N_ACT * CH) return;
    const float4* p = (const float4*)(in + base);
    float4 a = p[0], b = p[1];
    unsigned int w0 = (unsigned)f2bf(a.x) | ((unsigned)f2bf(a.y) << 16);
    unsigned int w1 = (unsigned)f2bf(a.z) | ((unsigned)f2bf(a.w) << 16);
    unsigned int w2 = (unsigned)f2bf(b.x) | ((unsigned)f2bf(b.y) << 16);
    unsigned int w3 = (unsigned)f2bf(b.z) | ((unsigned)f2bf(b.w) << 16);
    *(uint4*)(out + base) = make_uint4(w0, w1, w2, w3);
}

// K1b: pack W[k][cin][cout] fp32 into fragment-order bf16:
//   Wtp[(k*4+q)*4096 + (jkk*64 + lane)*8 + e]
// q = col-quarter (wave id), jkk = j*4+kk, lane = quad*16+lr,
// value = W[k][kk*32+quad*8+e][q*32+j*16+lr].
// -> each wave's 8 b-frag loads per k are 64 lanes x consecutive 16B (1 KB).
__global__ void prep_w(const float* __restrict__ W,
                       unsigned short* __restrict__ Wtp,
                       float* __restrict__ stats,
                       float* __restrict__ zpage) {
    int k = blockIdx.x;
    int t = threadIdx.x;
    if (k == 0 && t < 2 * CH) stats[t] = 0.0f;   // sums + sumsq
    if (k == 0 && t < 64) zpage[t] = 0.0f;       // 256 B zero row for gathers
    const float* wk = W + (size_t)k * CH * CH;
    for (int g = t; g < 2048; g += 256) {
        int q = g >> 9, r = g & 511;
        int jkk = r >> 6, lane = r & 63;
        int j = jkk >> 2, kk = jkk & 3;
        int lr = lane & 15, quad = lane >> 4;
        int cout = q * 32 + j * 16 + lr;
        int cin0 = kk * 32 + quad * 8;
        unsigned int wbuf[4];
        #pragma unroll
        for (int h = 0; h < 4; ++h) {
            unsigned short lo = f2bf(wk[(size_t)(cin0 + 2*h)     * CH + cout]);
            unsigned short hi = f2bf(wk[(size_t)(cin0 + 2*h + 1) * CH + cout]);
            wbuf[h] = (unsigned)lo | ((unsigned)hi << 16);
        }
        *(uint4*)(Wtp + ((size_t)(k * 4 + q) << 12) + (size_t)(jkk * 64 + lane) * 8)
            = make_uint4(wbuf[0], wbuf[1], wbuf[2], wbuf[3]);
    }
}

// K2: single-LDS-buffer, 2-barrier pipeline with SHORT register live ranges.
// Per k: MFMA phase (reads As + B regs) | barrier | stage A(k+1): gather ->
// immediate ds_write (G regs die here) + loadB(k+1) | barrier.
// Exposed gather latency overlaps the co-resident block's MFMA phase.
// No register state except acc(AGPR) + B survives the MFMA phase -> no spill.
__global__ __launch_bounds__(256, 2) void conv_mfma(
        const unsigned short* __restrict__ feat,   // [N][128] bf16
        const int* __restrict__ nbr,               // [27][N]
        const unsigned short* __restrict__ Wtp,    // packed (see prep_w)
        const unsigned short* __restrict__ zpage,  // 256 B of zeros
        float* __restrict__ out,                   // [N][128] conv result
        float* __restrict__ stats) {               // sums[128], sumsq[128]
    __shared__ __bf16 As[TM * CH];                 // 32 KB, rotated chunks
    __shared__ int idxL[NOFF * TM];                // 13.8 KB
    __shared__ float sred[256];                    // 1 KB

    const int t    = threadIdx.x;
    const int row0 = blockIdx.x * TM;
    const int wid  = t >> 6;
    const int lane = t & 63;
    const int lr   = lane & 15;
    const int quad = lane >> 4;

    // ---- stage the whole neighbor-index table once (coalesced)
    for (int e = t; e < NOFF * TM; e += 256) {
        int k = e >> 7, r = e & 127;
        int gr = row0 + r;
        idxL[e] = (gr < N_ACT) ? nbr[(size_t)k * N_ACT + gr] : -1;
    }
    __syncthreads();

    v4f acc[8][2];
    #pragma unroll
    for (int i = 0; i < 8; ++i) {
        acc[i][0] = (v4f){0.f, 0.f, 0.f, 0.f};
        acc[i][1] = (v4f){0.f, 0.f, 0.f, 0.f};
    }

    // staging coords: thread t gathers chunk sc (16B) of rows p*16+sr0
    const int sc  = t & 15;
    const int sr0 = t >> 4;
    const unsigned short* zsrc = zpage + sc * 8;

    v8bf B[8];           // single B fragment set (lives across MFMA phase)

    // gather + immediate LDS write: G regs live only inside this function
    auto stageA = [&](int k) {
        uint4 G[8];
        #pragma unroll
        for (int p = 0; p < 8; ++p) {
            int row = p * 16 + sr0;
            int idx = idxL[k * TM + row];
            const unsigned short* src =
                (idx >= 0) ? feat + ((size_t)idx << 7) + sc * 8 : zsrc;
            G[p] = *(const uint4*)src;
        }
        #pragma unroll
        for (int p = 0; p < 8; ++p) {
            int row = p * 16 + sr0;
            *(uint4*)(As + row * CH + (((sc + row) & 15) << 3)) = G[p];
        }
    };
    auto loadB = [&](int k) {
        const unsigned short* base =
            Wtp + ((size_t)(k * 4 + wid) << 12) + (size_t)lane * 8;
        #pragma unroll
        for (int jkk = 0; jkk < 8; ++jkk)
            B[jkk] = *(const v8bf*)(base + jkk * 512);
    };
    // i-blocked: per row-subtile load 4 a-frags (16 regs), fire 8 MFMAs
    auto mfmaPhase = [&]() {
        #pragma unroll
        for (int i = 0; i < 8; ++i) {
            const __bf16* rowp = As + (i * 16 + lr) * CH;
            v8bf a[4];
            #pragma unroll
            for (int kk = 0; kk < 4; ++kk)
                a[kk] = *(const v8bf*)(rowp + (((kk * 4 + quad + lr) & 15) << 3));
            #pragma unroll
            for (int kk = 0; kk < 4; ++kk) {
                acc[i][0] = __builtin_amdgcn_mfma_f32_16x16x32_bf16(
                    a[kk], B[kk], acc[i][0], 0, 0, 0);
                acc[i][1] = __builtin_amdgcn_mfma_f32_16x16x32_bf16(
                    a[kk], B[4 + kk], acc[i][1], 0, 0, 0);
            }
        }
    };

    // ---- prologue: stage k=0
    stageA(0);
    loadB(0);
    __syncthreads();

    // ---- k-loop: 2 barriers, single buffer, no G-hold across MFMA
    #pragma unroll 1
    for (int k = 0; k < NOFF; ++k) {
        mfmaPhase();
        if (k + 1 < NOFF) {
            __syncthreads();       // everyone done reading As / B consumed
            stageA(k + 1);         // gather -> immediate ds_write (G dies)
            loadB(k + 1);          // B latency hides behind gather drain
            __syncthreads();       // stage complete
        }
    }

    // ---- epilogue: store conv result + per-column partial stats
    float psum[2] = {0.f, 0.f};
    float psq[2]  = {0.f, 0.f};
    #pragma unroll
    for (int i = 0; i < 8; ++i) {
        #pragma unroll
        for (int r = 0; r < 4; ++r) {
            int grow = row0 + i * 16 + quad * 4 + r;
            if (grow < N_ACT) {
                #pragma unroll
                for (int j = 0; j < 2; ++j) {
                    float v = acc[i][j][r];
                    out[(size_t)grow * CH + wid * 32 + j * 16 + lr] = v;
                    psum[j] += v;
                    psq[j]  += v * v;
                }
            }
        }
    }
    #pragma unroll
    for (int j = 0; j < 2; ++j) {
        psum[j] += __shfl_xor(psum[j], 16, 64);
        psq[j]  += __shfl_xor(psq[j], 16, 64);
        psum[j] += __shfl_xor(psum[j], 32, 64);
        psq[j]  += __shfl_xor(psq[j], 32, 64);
    }
    if (quad == 0) {
        #pragma unroll
        for (int j = 0; j < 2; ++j) {
            int c = wid * 32 + j * 16 + lr;
            sred[c]       = psum[j];
            sred[128 + c] = psq[j];
        }
    }
    __syncthreads();
    if (t < CH) {
        atomicAdd(&stats[t],      sred[t]);
        atomicAdd(&stats[CH + t], sred[128 + t]);
    }
}

// K3: per-channel scale/shift from batch stats
__global__ void finalize_stats(const float* __restrict__ gamma,
                               const float* __restrict__ beta,
                               float* __restrict__ stats) {
    int c = threadIdx.x;
    if (c < CH) {
        float inv_n = 1.0f / (float)N_ACT;
        float mean  = stats[c] * inv_n;
        float var   = stats[CH + c] * inv_n - mean * mean;
        float sc    = gamma[c] * rsqrtf(var + 1e-4f);
        stats[2 * CH + c] = sc;
        stats[3 * CH + c] = beta[c] - mean * sc;
    }
}

// K4: out = relu(conv * scale[c] + shift[c]), float4
__global__ void bn_relu(const float* __restrict__ conv,
                        const float* __restrict__ stats,
                        float* __restrict__ out) {
    long long i = (long long)blockIdx.x * blockDim.x + threadIdx.x;
    if (i >= (long long)N_ACT * CH / 4) return;
    int c4 = (int)(i & 31) * 4;
    float4 v  = ((const float4*)conv)[i];
    float4 sc = *(const float4*)(stats + 2 * CH + c4);
    float4 sh = *(const float4*)(stats + 3 * CH + c4);
    float4 o;
    o.x = fmaxf(v.x * sc.x + sh.x, 0.f);
    o.y = fmaxf(v.y * sc.y + sh.y, 0.f);
    o.z = fmaxf(v.z * sc.z + sh.z, 0.f);
    o.w = fmaxf(v.w * sc.w + sh.w, 0.f);
    ((float4*)out)[i] = o;
}

extern "C" void kernel_launch(void* const* d_in, const int* in_sizes, int n_in,
                              void* d_out, int out_size, void* d_ws, size_t ws_size,
                              hipStream_t stream) {
    const float* features = (const float*)d_in[0];
    const int*   nbr      = (const int*)d_in[1];
    const float* W        = (const float*)d_in[2];
    const float* gamma    = (const float*)d_in[3];
    const float* beta     = (const float*)d_in[4];
    float* outp = (float*)d_out;

    char* ws = (char*)d_ws;
    // layout: feat_bf16 (51,200,000 B) | Wtp (884,736 B) | conv fp32
    // (102,400,000 B) | stats (512 floats) | zero page (256 B)
    unsigned short* feat_bf = (unsigned short*)ws;
    unsigned short* Wtp     = (unsigned short*)(ws + 51200000);
    float* conv             = (float*)(ws + 51200000 + 884736);
    float* stats            = (float*)(ws + 51200000 + 884736 + 102400000);
    float* zpage            = stats + 4 * CH;

    cast_feat<<<12500, 256, 0, stream>>>(features, feat_bf);
    prep_w<<<NOFF, 256, 0, stream>>>(W, Wtp, stats, zpage);
    conv_mfma<<<(N_ACT + TM - 1) / TM, 256, 0, stream>>>(
        feat_bf, nbr, Wtp, (const unsigned short*)zpage, conv, stats);
    finalize_stats<<<1, CH, 0, stream>>>(gamma, beta, stats);
    bn_relu<<<25000, 256, 0, stream>>>(conv, stats, outp);
}